// Round 4
// baseline (77.783 us; speedup 1.0000x reference)
//
#include <hip/hip_runtime.h>
#include <math.h>

// ColBERT pairwise late-interaction score — R13: exact R9 structure (best
// measured: 75.3 us total, kernel ~11.3 us) with ONE change: live b's are
// batched 4-at-a-time instead of 2, halving the number of
// {q-stage, barrier, q-norm, barrier, MFMA, barrier, finalize} rounds for the
// typical M=2-3 case.
//
// Session evidence (what NOT to retry):
//  - R10 (Lk split, 2 launches): +3.4 us — extra dispatch ~3 us; partial
//    kernel didn't shrink (latency-chain, not BW).
//  - R11 (cooperative grid sync): cg::sync spins ~90 us on gfx950. Dead.
//  - R12 (1024t block): kernel +1 us — wide-block barriers ate the
//    redistributed compute; serial chain phases unchanged.
// Fixed cost context: total ~= 64.4 us harness (268 MB poison fill 42.8 +
// ~20 us tiny reset dispatches) + kernel. Kernel floor ~= 2.7 us k-read BW +
// ~2 us dispatch + chain.
//
// out[b,o] = scale/sqrt(Lq*Lk) * sum_i log(sum_j exp(alpha*qn[b,i].kn[o,j]))/alpha
// Row b exactly zero if any q_mask[b,i] -> only M ~ 2-3 of 64 b's live.
// Numerics: S <= 1 -> alpha*S <= 12, exp never overflows; masked j adds -1e30
// before exp -> exact 0; valid j >= e^-12 so rowsum == 0 iff row fully
// k-masked (-inf -> zero). f16 rounding ~1e-3 vs 5.1e-2 threshold.

#define ALPHA 12.0f

constexpr int B_  = 64;
constexpr int LQ  = 32;
constexpr int O_  = 128;
constexpr int LK  = 256;
constexpr int D_  = 128;
constexpr int LDH = D_ + 8;        // f16 row stride 136 (272 B), 16B-aligned

typedef _Float16 half8   __attribute__((ext_vector_type(8)));
typedef _Float16 half4_t __attribute__((ext_vector_type(4)));
typedef float    f32x4   __attribute__((ext_vector_type(4)));

__global__ __launch_bounds__(256, 1)
void colbert_fused_kernel(const float* __restrict__ q,       // [B, Lq, D]
                          const float* __restrict__ k,       // [O, Lk, D]
                          const int*  __restrict__ q_mask,   // [B, Lq] 0/1
                          const int*  __restrict__ k_mask,   // [O, Lk] 0/1
                          const float* __restrict__ logit_scale,
                          float* __restrict__ out)           // [B, O]
{
    __shared__ _Float16 kl[LK][LDH];        // 69632 B
    __shared__ _Float16 ql4[4][LQ][LDH];    // 34816 B (quad of q tiles)
    __shared__ float rk[LK];                // 1/||k_j||
    __shared__ float bjs[LK];               // 0 or -1e30
    __shared__ float rqa4[4][LQ];           // ALPHA/||q_i||
    __shared__ float part4[4][2][LQ];       // [member][col-half][row]
    __shared__ int   lbm[B_ + 1];           // [0]=M, [1+m]=live b

    const int o     = blockIdx.x;
    const int t     = threadIdx.x;
    const int lane  = t & 63;
    const int w     = t >> 6;
    const int row16 = lane & 15;
    const int quad  = lane >> 4;

    // ---- wave 0 ONLY: q_mask scan + ballot + dead-row zeroing ----
    if (w == 0) {
        const int4* qm4 = (const int4*)q_mask;     // [64][32] ints, lane = b
        int4 mm[8];
        #pragma unroll
        for (int u = 0; u < 8; ++u)
            mm[u] = qm4[lane * 8 + u];
        int any = 0;
        #pragma unroll
        for (int u = 0; u < 8; ++u)
            any |= mm[u].x | mm[u].y | mm[u].z | mm[u].w;
        const bool live = (any == 0);
        unsigned long long mb = __ballot(live);
        if (live) {
            int rank = __popcll(mb & ((1ull << lane) - 1ull));
            lbm[1 + rank] = lane;
        } else {
            out[lane * O_ + o] = 0.0f;             // dead row -> exact zero
        }
        if (lane == 0) lbm[0] = (int)__popcll(mb);
    }

    // ---- all waves: k tile loads (waves 1-3 start here immediately) ----
    const float4* kg = (const float4*)(k + (size_t)o * LK * D_);
    float4 kv[16];
    #pragma unroll
    for (int r = 0; r < 16; ++r)
        kv[r] = kg[t + 256 * r];                   // rows 0..127, coalesced
    const int   km = k_mask[o * LK + t];           // row j = t
    const float ls = logit_scale[0];

    // convert half 0, load+convert half 1
    #pragma unroll
    for (int r = 0; r < 16; ++r) {
        int idx = t + 256 * r;
        int j = idx >> 5, c4 = idx & 31;
        half4_t hh;
        hh[0] = (_Float16)kv[r].x; hh[1] = (_Float16)kv[r].y;
        hh[2] = (_Float16)kv[r].z; hh[3] = (_Float16)kv[r].w;
        *(half4_t*)&kl[j][c4 * 4] = hh;
    }
    #pragma unroll
    for (int r = 0; r < 16; ++r)
        kv[r] = kg[4096 + t + 256 * r];            // rows 128..255
    #pragma unroll
    for (int r = 0; r < 16; ++r) {
        int idx = 4096 + t + 256 * r;
        int j = idx >> 5, c4 = idx & 31;
        half4_t hh;
        hh[0] = (_Float16)kv[r].x; hh[1] = (_Float16)kv[r].y;
        hh[2] = (_Float16)kv[r].z; hh[3] = (_Float16)kv[r].w;
        *(half4_t*)&kl[j][c4 * 4] = hh;
    }
    __syncthreads();                               // kl + lbm visible

    const int M = lbm[0];
    if (M == 0) return;                            // block-uniform

    const float scale  = fminf(__expf(ls), 100.0f);
    const float inv_ln = 1.0f / (sqrtf((float)(LQ * LK)) + 1e-6f);

    // ---- live b's in quads; iteration 0 overlaps q loads with k norms ----
    int midx = 0;
    bool first = true;
    while (midx < M) {
        int bq[4];
        #pragma unroll
        for (int m = 0; m < 4; ++m) {
            int mi = midx + m;
            bq[m] = lbm[1 + ((mi < M) ? mi : (M - 1))];   // clamp: dup benign
        }
        const int nb = (M - midx < 4) ? (M - midx) : 4;   // live in batch
        midx += 4;

        // issue q loads for the whole batch FIRST (latency hides under norms)
        float4 qv[4][4];
        #pragma unroll
        for (int m = 0; m < 4; ++m) {
            const float4* qg = (const float4*)(q + (size_t)bq[m] * LQ * D_);
            #pragma unroll
            for (int r = 0; r < 4; ++r)
                qv[m][r] = qg[t + 256 * r];
        }

        // k norms + mask bias on iteration 0 (DS/VALU while q in flight)
        if (first) {
            float ss = 0.f;
            #pragma unroll
            for (int p = 0; p < 16; ++p) {
                half8 hh = *(const half8*)&kl[t][p * 8];
                #pragma unroll
                for (int e = 0; e < 8; ++e) {
                    float x = (float)hh[e];
                    ss = fmaf(x, x, ss);
                }
            }
            rk[t]  = 1.0f / fmaxf(sqrtf(ss), 1e-12f);
            bjs[t] = (km != 0) ? -1e30f : 0.0f;
            first = false;
        }

        // convert + stage q quad
        #pragma unroll
        for (int m = 0; m < 4; ++m) {
            #pragma unroll
            for (int r = 0; r < 4; ++r) {
                int idx = t + 256 * r;             // [32][32] float4
                int i = idx >> 5, c4 = idx & 31;
                half4_t hh;
                hh[0] = (_Float16)qv[m][r].x; hh[1] = (_Float16)qv[m][r].y;
                hh[2] = (_Float16)qv[m][r].z; hh[3] = (_Float16)qv[m][r].w;
                *(half4_t*)&ql4[m][i][c4 * 4] = hh;
            }
        }
        __syncthreads();                           // ql4 + rk/bjs visible

        // q norms: t<128 covers all four members (mem = t>>5, i = t&31)
        if (t < 128) {
            const int mem = t >> 5, i = t & 31;
            float ss = 0.f;
            #pragma unroll
            for (int p = 0; p < 16; ++p) {
                half8 hh = *(const half8*)&ql4[mem][i][p * 8];
                #pragma unroll
                for (int e = 0; e < 8; ++e) {
                    float x = (float)hh[e];
                    ss = fmaf(x, x, ss);
                }
            }
            rqa4[mem][i] = ALPHA / fmaxf(sqrtf(ss), 1e-12f);
        }
        __syncthreads();

        // MFMA: wave w -> rows [16*(w>>1), +16), cols [(w&1)*128, +128)
        // gp loop: pair (0,1) then pair (2,3) — exact R9 inner code per gp.
        const int i0 = (w >> 1) * 16;
        const int j0 = (w & 1) * 128;
        const int ngp = (nb > 2) ? 2 : 1;          // block-uniform

        for (int gp = 0; gp < ngp; ++gp) {
            const int m0 = gp * 2, m1 = gp * 2 + 1;

            half8 afrag[2][4];
            #pragma unroll
            for (int pb = 0; pb < 2; ++pb)
                #pragma unroll
                for (int kk = 0; kk < 4; ++kk)
                    afrag[pb][kk] =
                        *(const half8*)&ql4[m0 + pb][i0 + row16][kk * 32 + quad * 8];

            float rqv[2][4];
            #pragma unroll
            for (int pb = 0; pb < 2; ++pb)
                #pragma unroll
                for (int rg = 0; rg < 4; ++rg)
                    rqv[pb][rg] = rqa4[m0 + pb][i0 + quad * 4 + rg];

            float esum[2][4] = {{0.f,0.f,0.f,0.f},{0.f,0.f,0.f,0.f}};
            #pragma unroll
            for (int c = 0; c < 8; ++c) {
                const int jt = j0 + c * 16;
                f32x4 acc0 = {0.f, 0.f, 0.f, 0.f};
                f32x4 acc1 = {0.f, 0.f, 0.f, 0.f};
                #pragma unroll
                for (int kk = 0; kk < 4; ++kk) {
                    half8 bfrag =
                        *(const half8*)&kl[jt + row16][kk * 32 + quad * 8];
                    acc0 = __builtin_amdgcn_mfma_f32_16x16x32_f16(
                               afrag[0][kk], bfrag, acc0, 0, 0, 0);
                    acc1 = __builtin_amdgcn_mfma_f32_16x16x32_f16(
                               afrag[1][kk], bfrag, acc1, 0, 0, 0);
                }
                // C layout: col = lane&15 (j), row = quad*4+reg (i)
                const float rkj = rk[jt + row16];
                const float bb  = bjs[jt + row16];
                #pragma unroll
                for (int rg = 0; rg < 4; ++rg) {
                    esum[0][rg] += __expf(acc0[rg] * rqv[0][rg] * rkj + bb);
                    esum[1][rg] += __expf(acc1[rg] * rqv[1][rg] * rkj + bb);
                }
            }
            #pragma unroll
            for (int pb = 0; pb < 2; ++pb) {
                #pragma unroll
                for (int rg = 0; rg < 4; ++rg) {
                    float e = esum[pb][rg];
                    e += __shfl_xor(e, 1);
                    e += __shfl_xor(e, 2);
                    e += __shfl_xor(e, 4);
                    e += __shfl_xor(e, 8);
                    esum[pb][rg] = e;
                }
                if (row16 == 0)
                    #pragma unroll
                    for (int rg = 0; rg < 4; ++rg)
                        part4[m0 + pb][w & 1][i0 + quad * 4 + rg] = esum[pb][rg];
            }
            (void)m1;
        }
        __syncthreads();

        // finalize all batch members: waves 0-1 (mem = t>>5; dup writes benign)
        if (t < 128) {
            const int mem = t >> 5, i = t & 31;
            if (mem < nb || mem == 0) {            // clamped dups: same value
                float s = part4[mem][0][i] + part4[mem][1][i];
                bool badrow = (s <= 0.f);          // row fully k-masked
                float lse = __logf(fmaxf(s, 1e-38f));
                float tot = lse;
                tot += __shfl_xor(tot, 16);
                tot += __shfl_xor(tot, 8);
                tot += __shfl_xor(tot, 4);
                tot += __shfl_xor(tot, 2);
                tot += __shfl_xor(tot, 1);
                unsigned long long zb = __ballot(badrow);
                if (i == 0 && mem < nb) {
                    unsigned long long half_mask =
                        ((lane >> 5) == 0) ? 0xFFFFFFFFull
                                           : 0xFFFFFFFF00000000ull;
                    float res = 0.f;
                    if ((zb & half_mask) == 0ull)
                        res = (tot * (1.0f / ALPHA)) * inv_ln * scale;
                    out[bq[mem] * O_ + o] = res;
                }
            }
        }
        // next-iter ql4 writes are gated by the post-staging barrier — same
        // protection structure as R9 (part4 reads complete before any wave
        // can pass the staging barrier of the next iteration).
    }
}

extern "C" void kernel_launch(void* const* d_in, const int* in_sizes, int n_in,
                              void* d_out, int out_size, void* d_ws, size_t ws_size,
                              hipStream_t stream) {
    const float* q           = (const float*)d_in[0];
    const float* k           = (const float*)d_in[1];
    const int*   q_mask      = (const int*)d_in[2];
    const int*   k_mask      = (const int*)d_in[3];
    const float* logit_scale = (const float*)d_in[4];
    float* out = (float*)d_out;

    colbert_fused_kernel<<<O_, 256, 0, stream>>>(q, k, q_mask, k_mask,
                                                 logit_scale, out);
}

// Round 5
// 77.384 us; speedup vs baseline: 1.0052x; 1.0052x over previous
//
#include <hip/hip_runtime.h>
#include <math.h>

// ColBERT pairwise late-interaction score — R14: R9 skeleton (best measured:
// 75.3/75.7 us total, kernel ~11.3 us) with the q LDS round-trip removed.
//
// Key statistic: E[live b] = 64 * 0.9^32 ~ 2.2 -> M ~= 2, so the pair loop
// runs ONCE. R13 (quad batching) removed zero iterations (+reg pressure, +2us).
// R12 (16 waves) redistributed one-shot phases and paid 1024t barriers (+1us).
// R10 (2 launches) paid ~3us dispatch. R11 (coop grid sync) spins ~90us. All
// reverted; this round only DELETES work from the proven R9 chain:
//
//  - ALL waves scan q_mask redundantly (8 KB, L1-shared after first wave) ->
//    live-b list in registers everywhere; lbm LDS publish eliminated; b0/b1
//    known BEFORE k staging, so first-pair q gathers issue under the k loads.
//  - q never touches LDS: each lane gathers its OWN A-fragment elements
//    (row i0+row16, cols kk*32+quad*8) from global f32 (32 KB, L2-broadcast
//    across the 128 blocks), computes q row norms in-register (32-elem
//    partial + shfl_xor(16,32) across quads + shfl redistribution for the
//    C-layout rows), converts to f16 frags in regs.
//  - Phases deleted vs R9: q-stage, q-norm-from-LDS, one barrier, lbm LDS.
//    k path, MFMA inner loop, finalize: byte-identical R9.
//
// out[b,o] = scale/sqrt(Lq*Lk) * sum_i log(sum_j exp(alpha*qn[b,i].kn[o,j]))/alpha
// Row b exactly zero if any q_mask[b,i]. Numerics: S <= 1 -> alpha*S <= 12,
// exp never overflows; masked j adds -1e30 before exp -> exact 0; valid j
// >= e^-12 so rowsum == 0 iff row fully k-masked (-inf -> zero). f16 input
// rounding ~1e-3 vs 5.1e-2 threshold; q norms now computed in f32 (closer to
// reference than R9's f16-LDS norms).

#define ALPHA 12.0f

constexpr int B_  = 64;
constexpr int LQ  = 32;
constexpr int O_  = 128;
constexpr int LK  = 256;
constexpr int D_  = 128;
constexpr int LDH = D_ + 8;        // f16 row stride 136 (272 B), 16B-aligned

typedef _Float16 half8   __attribute__((ext_vector_type(8)));
typedef _Float16 half4_t __attribute__((ext_vector_type(4)));
typedef float    f32x4   __attribute__((ext_vector_type(4)));

__global__ __launch_bounds__(256, 1)
void colbert_fused_kernel(const float* __restrict__ q,       // [B, Lq, D]
                          const float* __restrict__ k,       // [O, Lk, D]
                          const int*  __restrict__ q_mask,   // [B, Lq] 0/1
                          const int*  __restrict__ k_mask,   // [O, Lk] 0/1
                          const float* __restrict__ logit_scale,
                          float* __restrict__ out)           // [B, O]
{
    __shared__ _Float16 kl[LK][LDH];        // 69632 B
    __shared__ float rk[LK];                // 1/||k_j||
    __shared__ float bjs[LK];               // 0 or -1e30
    __shared__ float part2[2][2][LQ];       // [pair][col-half][row]

    const int o     = blockIdx.x;
    const int t     = threadIdx.x;
    const int lane  = t & 63;
    const int w     = t >> 6;
    const int row16 = lane & 15;
    const int quad  = lane >> 4;

    // ---- issue q_mask scan loads first (8 KB, L1-shared across waves) ----
    const int4* qm4 = (const int4*)q_mask;         // [64][32] ints, lane = b
    int4 mm[8];
    #pragma unroll
    for (int u = 0; u < 8; ++u)
        mm[u] = qm4[lane * 8 + u];

    // ---- k tile half-1 loads (no dependency on the scan) ----
    const float4* kg = (const float4*)(k + (size_t)o * LK * D_);
    float4 kv[16];
    #pragma unroll
    for (int r = 0; r < 16; ++r)
        kv[r] = kg[t + 256 * r];                   // rows 0..127, coalesced
    const int   km = k_mask[o * LK + t];           // row j = t
    const float ls = logit_scale[0];

    // ---- scan compute: live-b ballot, in registers, ALL waves ----
    int any = 0;
    #pragma unroll
    for (int u = 0; u < 8; ++u)
        any |= mm[u].x | mm[u].y | mm[u].z | mm[u].w;
    const bool live = (any == 0);
    unsigned long long mb = __ballot(live);
    if (w == 0 && !live)
        out[lane * O_ + o] = 0.0f;                 // dead row -> exact zero
    const int M = (int)__popcll(mb);
    if (M == 0) return;                            // block-uniform, pre-barrier

    // first pair of live b's
    unsigned long long rem = mb;
    int b0 = (int)__builtin_ctzll(rem);
    rem &= rem - 1ull;
    int b1 = rem ? (int)__builtin_ctzll(rem) : b0; // dup benign (M odd)
    if (rem) rem &= rem - 1ull;

    const int i0 = (w >> 1) * 16;                  // wave's q-row block
    const int j0 = (w & 1) * 128;                  // wave's k-col block
    const int qrow = i0 + row16;

    // ---- q gathers for first pair: issue NOW, land under k staging ----
    // lane reads its own A-frag elems: q[b][qrow][kk*32 + quad*8 + 0..7]
    float4 qf0[8], qf1[8];
    {
        const float* qb0 = q + ((size_t)b0 * LQ + qrow) * D_;
        const float* qb1 = q + ((size_t)b1 * LQ + qrow) * D_;
        #pragma unroll
        for (int kk = 0; kk < 4; ++kk) {
            #pragma unroll
            for (int hv = 0; hv < 2; ++hv) {
                qf0[kk * 2 + hv] =
                    *(const float4*)(qb0 + kk * 32 + quad * 8 + hv * 4);
                qf1[kk * 2 + hv] =
                    *(const float4*)(qb1 + kk * 32 + quad * 8 + hv * 4);
            }
        }
    }

    // ---- convert k half-1, load+convert half-2 (exact R9 path) ----
    #pragma unroll
    for (int r = 0; r < 16; ++r) {
        int idx = t + 256 * r;
        int j = idx >> 5, c4 = idx & 31;
        half4_t hh;
        hh[0] = (_Float16)kv[r].x; hh[1] = (_Float16)kv[r].y;
        hh[2] = (_Float16)kv[r].z; hh[3] = (_Float16)kv[r].w;
        *(half4_t*)&kl[j][c4 * 4] = hh;
    }
    #pragma unroll
    for (int r = 0; r < 16; ++r)
        kv[r] = kg[4096 + t + 256 * r];            // rows 128..255
    #pragma unroll
    for (int r = 0; r < 16; ++r) {
        int idx = 4096 + t + 256 * r;
        int j = idx >> 5, c4 = idx & 31;
        half4_t hh;
        hh[0] = (_Float16)kv[r].x; hh[1] = (_Float16)kv[r].y;
        hh[2] = (_Float16)kv[r].z; hh[3] = (_Float16)kv[r].w;
        *(half4_t*)&kl[j][c4 * 4] = hh;
    }

    // ---- q norms + A-frags fully in registers (no barrier needed) ----
    float rqv0[4], rqv1[4];
    half8 afrag0[4], afrag1[4];
    {
        float ss0 = 0.f, ss1 = 0.f;
        #pragma unroll
        for (int v = 0; v < 8; ++v) {
            #pragma unroll
            for (int e = 0; e < 4; ++e) {
                float x0 = ((const float*)&qf0[v])[e];
                float x1 = ((const float*)&qf1[v])[e];
                ss0 = fmaf(x0, x0, ss0);
                ss1 = fmaf(x1, x1, ss1);
            }
        }
        // combine the 4 quad-chunks of row qrow (lane = row16 + 16*quad)
        ss0 += __shfl_xor(ss0, 16); ss0 += __shfl_xor(ss0, 32);
        ss1 += __shfl_xor(ss1, 16); ss1 += __shfl_xor(ss1, 32);
        // C layout rows are i0 + quad*4 + rg -> fetch from lane quad*4+rg
        #pragma unroll
        for (int rg = 0; rg < 4; ++rg) {
            float n0 = __shfl(ss0, quad * 4 + rg);
            float n1 = __shfl(ss1, quad * 4 + rg);
            rqv0[rg] = ALPHA / fmaxf(sqrtf(n0), 1e-12f);
            rqv1[rg] = ALPHA / fmaxf(sqrtf(n1), 1e-12f);
        }
        #pragma unroll
        for (int kk = 0; kk < 4; ++kk) {
            half8 h0, h1;
            #pragma unroll
            for (int e = 0; e < 4; ++e) {
                h0[e]     = (_Float16)((const float*)&qf0[kk * 2])[e];
                h0[e + 4] = (_Float16)((const float*)&qf0[kk * 2 + 1])[e];
                h1[e]     = (_Float16)((const float*)&qf1[kk * 2])[e];
                h1[e + 4] = (_Float16)((const float*)&qf1[kk * 2 + 1])[e];
            }
            afrag0[kk] = h0;
            afrag1[kk] = h1;
        }
    }

    __syncthreads();                               // barrier 1: kl visible

    // ---- k norms + mask bias (row t), then publish ----
    {
        float ss = 0.f;
        #pragma unroll
        for (int p = 0; p < 16; ++p) {
            half8 hh = *(const half8*)&kl[t][p * 8];
            #pragma unroll
            for (int e = 0; e < 8; ++e) {
                float x = (float)hh[e];
                ss = fmaf(x, x, ss);
            }
        }
        rk[t]  = 1.0f / fmaxf(sqrtf(ss), 1e-12f);
        bjs[t] = (km != 0) ? -1e30f : 0.0f;
    }
    __syncthreads();                               // barrier 2: rk/bjs visible

    const float scale  = fminf(__expf(ls), 100.0f);
    const float inv_ln = 1.0f / (sqrtf((float)(LQ * LK)) + 1e-6f);

    // ---- pair loop (runs once for M<=2) ----
    int midx = 0;
    while (true) {
        float esum[2][4] = {{0.f,0.f,0.f,0.f},{0.f,0.f,0.f,0.f}};
        #pragma unroll
        for (int c = 0; c < 8; ++c) {
            const int jt = j0 + c * 16;
            f32x4 acc0 = {0.f, 0.f, 0.f, 0.f};
            f32x4 acc1 = {0.f, 0.f, 0.f, 0.f};
            #pragma unroll
            for (int kk = 0; kk < 4; ++kk) {
                half8 bfrag =
                    *(const half8*)&kl[jt + row16][kk * 32 + quad * 8];
                acc0 = __builtin_amdgcn_mfma_f32_16x16x32_f16(
                           afrag0[kk], bfrag, acc0, 0, 0, 0);
                acc1 = __builtin_amdgcn_mfma_f32_16x16x32_f16(
                           afrag1[kk], bfrag, acc1, 0, 0, 0);
            }
            // C layout: col = lane&15 (j), row = quad*4+reg (i)
            const float rkj = rk[jt + row16];
            const float bb  = bjs[jt + row16];
            #pragma unroll
            for (int rg = 0; rg < 4; ++rg) {
                esum[0][rg] += __expf(acc0[rg] * rqv0[rg] * rkj + bb);
                esum[1][rg] += __expf(acc1[rg] * rqv1[rg] * rkj + bb);
            }
        }
        #pragma unroll
        for (int pb = 0; pb < 2; ++pb) {
            #pragma unroll
            for (int rg = 0; rg < 4; ++rg) {
                float e = esum[pb][rg];
                e += __shfl_xor(e, 1);
                e += __shfl_xor(e, 2);
                e += __shfl_xor(e, 4);
                e += __shfl_xor(e, 8);
                esum[pb][rg] = e;
            }
            if (row16 == 0)
                #pragma unroll
                for (int rg = 0; rg < 4; ++rg)
                    part2[pb][w & 1][i0 + quad * 4 + rg] = esum[pb][rg];
        }
        __syncthreads();                           // barrier 3: part2 visible

        // finalize both pair members (b1==b0 double-write benign)
        if (t < 64) {
            const int pb = t >> 5, i = t & 31;
            float s = part2[pb][0][i] + part2[pb][1][i];
            bool badrow = (s <= 0.f);              // row fully k-masked
            float lse = __logf(fmaxf(s, 1e-38f));
            float tot = lse;
            tot += __shfl_xor(tot, 16);
            tot += __shfl_xor(tot, 8);
            tot += __shfl_xor(tot, 4);
            tot += __shfl_xor(tot, 2);
            tot += __shfl_xor(tot, 1);
            unsigned long long zb = __ballot(badrow);
            if (i == 0) {
                unsigned long long half_mask =
                    (pb == 0) ? 0xFFFFFFFFull : 0xFFFFFFFF00000000ull;
                float res = 0.f;
                if ((zb & half_mask) == 0ull)
                    res = (tot * (1.0f / ALPHA)) * inv_ln * scale;
                out[((pb == 0) ? b0 : b1) * O_ + o] = res;
            }
        }

        midx += 2;
        if (midx >= M) break;

        // ---- next pair (rare: M>2). Gather q, norms, frags in regs. ----
        b0 = (int)__builtin_ctzll(rem);
        rem &= rem - 1ull;
        b1 = rem ? (int)__builtin_ctzll(rem) : b0;
        if (rem) rem &= rem - 1ull;
        {
            const float* qb0 = q + ((size_t)b0 * LQ + qrow) * D_;
            const float* qb1 = q + ((size_t)b1 * LQ + qrow) * D_;
            #pragma unroll
            for (int kk = 0; kk < 4; ++kk) {
                #pragma unroll
                for (int hv = 0; hv < 2; ++hv) {
                    qf0[kk * 2 + hv] =
                        *(const float4*)(qb0 + kk * 32 + quad * 8 + hv * 4);
                    qf1[kk * 2 + hv] =
                        *(const float4*)(qb1 + kk * 32 + quad * 8 + hv * 4);
                }
            }
        }
        float ss0 = 0.f, ss1 = 0.f;
        #pragma unroll
        for (int v = 0; v < 8; ++v) {
            #pragma unroll
            for (int e = 0; e < 4; ++e) {
                float x0 = ((const float*)&qf0[v])[e];
                float x1 = ((const float*)&qf1[v])[e];
                ss0 = fmaf(x0, x0, ss0);
                ss1 = fmaf(x1, x1, ss1);
            }
        }
        ss0 += __shfl_xor(ss0, 16); ss0 += __shfl_xor(ss0, 32);
        ss1 += __shfl_xor(ss1, 16); ss1 += __shfl_xor(ss1, 32);
        #pragma unroll
        for (int rg = 0; rg < 4; ++rg) {
            float n0 = __shfl(ss0, quad * 4 + rg);
            float n1 = __shfl(ss1, quad * 4 + rg);
            rqv0[rg] = ALPHA / fmaxf(sqrtf(n0), 1e-12f);
            rqv1[rg] = ALPHA / fmaxf(sqrtf(n1), 1e-12f);
        }
        #pragma unroll
        for (int kk = 0; kk < 4; ++kk) {
            half8 h0, h1;
            #pragma unroll
            for (int e = 0; e < 4; ++e) {
                h0[e]     = (_Float16)((const float*)&qf0[kk * 2])[e];
                h0[e + 4] = (_Float16)((const float*)&qf0[kk * 2 + 1])[e];
                h1[e]     = (_Float16)((const float*)&qf1[kk * 2])[e];
                h1[e + 4] = (_Float16)((const float*)&qf1[kk * 2 + 1])[e];
            }
            afrag0[kk] = h0;
            afrag1[kk] = h1;
        }
        __syncthreads();   // part2 reads of previous finalize complete
    }
}

extern "C" void kernel_launch(void* const* d_in, const int* in_sizes, int n_in,
                              void* d_out, int out_size, void* d_ws, size_t ws_size,
                              hipStream_t stream) {
    const float* q           = (const float*)d_in[0];
    const float* k           = (const float*)d_in[1];
    const int*   q_mask      = (const int*)d_in[2];
    const int*   k_mask      = (const int*)d_in[3];
    const float* logit_scale = (const float*)d_in[4];
    float* out = (float*)d_out;

    colbert_fused_kernel<<<O_, 256, 0, stream>>>(q, k, q_mask, k_mask,
                                                 logit_scale, out);
}